// Round 1
// baseline (677.199 us; speedup 1.0000x reference)
//
#include <hip/hip_runtime.h>

#define NIMG 16
#define CI   128
#define CO   256
#define HH   128
#define WW   128
#define HP   130
#define WP   130

typedef short bf16x8 __attribute__((ext_vector_type(8)));
typedef float f32x4  __attribute__((ext_vector_type(4)));

typedef __attribute__((address_space(3))) unsigned int as3_u32;
typedef __attribute__((address_space(1))) const unsigned int as1_u32;

__device__ __forceinline__ unsigned short f2bf(float f) {
    unsigned u = __builtin_bit_cast(unsigned, f);
    unsigned r = u + 0x7fffu + ((u >> 16) & 1u);   // RNE
    return (unsigned short)(r >> 16);
}

__device__ __forceinline__ void gload16(const unsigned short* g, void* lds) {
    // 16B per lane, HW writes lds_base + lane*16 (linear); source addr is per-lane.
    __builtin_amdgcn_global_load_lds((as1_u32*)g, (as3_u32*)lds, 16, 0, 0);
}

// ---------------------------------------------------------------------------
// Prep 1: weights OIHW fp32 -> wt[tap][co][ci] bf16, scaled by kx[i]*kx[j]
// ---------------------------------------------------------------------------
__global__ void xform_w(const float* __restrict__ wsrc, unsigned short* __restrict__ wt) {
    int idx = blockIdx.x * 256 + threadIdx.x;       // (tap*256 + o)*128 + ci
    int ci   = idx & 127;
    int rest = idx >> 7;
    int o    = rest & 255;
    int tap  = rest >> 8;
    int i = tap / 3, j = tap - 3 * i;
    const float s0 = 0.7f;
    float si = (i == 1) ? 1.0f : s0;
    float sj = (j == 1) ? 1.0f : s0;
    float v = wsrc[((o * 128 + ci) * 3 + i) * 3 + j] * si * sj;
    wt[idx] = f2bf(v);
}

// ---------------------------------------------------------------------------
// Prep 2: x NCHW fp32 -> PADDED xt [n][hp 0..129][wp 0..129][ci] bf16.
// Borders zeroed. LDS transpose with XOR swizzle on c bits [2:1] keyed by
// (w>>3)&3 so phase-1 scalar writes are bank-conflict-free; phase-2 reads
// b128 and un-swizzles the 4 words in-register.
// ---------------------------------------------------------------------------
__global__ __launch_bounds__(256) void xform_x(const float* __restrict__ x,
                                               unsigned short* __restrict__ xt) {
    int bid = blockIdx.x;                  // n*130 + hp
    int n = bid / 130, hp = bid - n * 130;
    int t = threadIdx.x;
    size_t rowbase = (size_t)bid * WP * CI;          // elems at (n,hp,0,0)

    if (hp == 0 || hp == 129) {                      // zero border row
        int4 z = make_int4(0, 0, 0, 0);
        for (int c = t; c < (WP * CI * 2) / 16; c += 256)
            *(int4*)((char*)(xt + rowbase) + (size_t)c * 16) = z;
        return;
    }
    int h = hp - 1;

    __shared__ __align__(16) unsigned short ls[128][136];

    int w = t & 127, ch = t >> 7;
    int px = ((w >> 3) & 3) << 1;          // XOR on c bits [2:1]
#pragma unroll 8
    for (int cc = 0; cc < 64; ++cc) {
        int c = cc * 2 + ch;
        float v = x[(((size_t)n * CI + c) * HH + h) * WW + w];
        ls[w][c ^ px] = f2bf(v);
    }
    // w-border zero chunks (independent of LDS)
    if (t < 32) {
        int side = t >> 4, part = t & 15;
        size_t o = rowbase + (side ? (size_t)129 * CI : 0) + part * 8;
        *(int4*)(xt + o) = make_int4(0, 0, 0, 0);
    }
    __syncthreads();

    size_t obase = rowbase + CI;           // wp = 1
    for (int it = 0; it < 8; ++it) {
        int chunk = it * 256 + t;          // 0..2047
        int ww = chunk >> 4, cp = chunk & 15;
        int4 v = *(const int4*)&ls[ww][cp * 8];
        int s = (ww >> 3) & 3;
        int4 o = v;
        if (s & 1) o = make_int4(o.y, o.x, o.w, o.z);
        if (s & 2) o = make_int4(o.z, o.w, o.x, o.y);
        *(int4*)((char*)(xt + obase) + (size_t)chunk * 16) = o;
    }
}

// ---------------------------------------------------------------------------
// Main: implicit-GEMM conv, 128 px x 128 co per block, 4 waves, acc 4x4.
// Per kc: stage 3x130-px halo (padded xt -> no predication) via
// global_load_lds width 16; XOR slot swizzle (p>>1)&3 applied on the
// GLOBAL source (LDS stays linear) and undone on the ds_read side.
// ---------------------------------------------------------------------------
__global__ __launch_bounds__(256) void conv_mfma(const unsigned short* __restrict__ xt,
                                                 const unsigned short* __restrict__ wt,
                                                 const float* __restrict__ bias,
                                                 float* __restrict__ out) {
    int bid = blockIdx.x;
    int bn  = bid & 1;            // co half
    int bm  = bid >> 1;           // (n,h)
    int n = bm >> 7, h = bm & 127;
    int tid  = threadIdx.x;
    int lane = tid & 63, wv = tid >> 6;
    int mw = wv & 1, nw = wv >> 1;
    int lr = lane & 15;
    int lq = lane >> 4;

    // xs: 1792 chunks * 16B = 28672B (real data: 390 px * 64B = 24960B).
    // Epilogue scratch aliases the same region (used strictly after k-loop).
    __shared__ __align__(1024) char smem[28672];
    unsigned short* xs = (unsigned short*)smem;

    f32x4 acc[4][4];
    const f32x4 zero = {0.0f, 0.0f, 0.0f, 0.0f};
    for (int mi = 0; mi < 4; ++mi)
        for (int ni = 0; ni < 4; ++ni) acc[mi][ni] = zero;

    int pm[4];
    for (int mi = 0; mi < 4; ++mi) pm[mi] = mw * 64 + mi * 16 + lr;
    int bo[4];
    for (int ni = 0; ni < 4; ++ni) {
        int co = bn * 128 + nw * 64 + ni * 16 + lr;
        bo[ni] = co * CI + lq * 8;
    }

    // kc-invariant staging source offsets (elems). chunk c = (p<<2)|slot,
    // source part q = slot ^ ((p>>1)&3)  (swizzle on source, LDS linear).
    int goffs[7];
    int nbase = n * (HP * WP * CI);
#pragma unroll
    for (int i = 0; i < 7; ++i) {
        int c = wv * 448 + i * 64 + lane;
        int pp = (c < 1560) ? (c >> 2) : 0;       // clamp tail chunks in-bounds
        int slot = c & 3;
        int q = slot ^ ((pp >> 1) & 3);
        int dh = (pp * 505) >> 16;                // pp / 130 for pp < 390
        int wp = pp - dh * 130;
        goffs[i] = nbase + ((h + dh) * WP + wp) * CI + q * 8;
    }

#pragma unroll 1
    for (int kc = 0; kc < 4; ++kc) {
        __syncthreads();
#pragma unroll
        for (int i = 0; i < 7; ++i)
            gload16(xt + goffs[i] + kc * 32, smem + wv * 7168 + i * 1024);
        __syncthreads();

        const unsigned short* wk = wt + kc * 32;
#pragma unroll
        for (int tap = 0; tap < 9; ++tap) {
            int di = tap / 3, dj = tap - 3 * di;
            int pd = di * 130 + dj;
            bf16x8 a[4], b[4];
#pragma unroll
            for (int mi = 0; mi < 4; ++mi) {
                int p = pd + pm[mi];
                int sw = (p >> 1) & 3;
                a[mi] = *(const bf16x8*)(xs + p * 32 + ((lq ^ sw) << 3));
            }
            const unsigned short* wtap = wk + (size_t)tap * CO * CI;
#pragma unroll
            for (int ni = 0; ni < 4; ++ni)
                b[ni] = *(const bf16x8*)(wtap + bo[ni]);
#pragma unroll
            for (int mi = 0; mi < 4; ++mi)
#pragma unroll
                for (int ni = 0; ni < 4; ++ni)
                    acc[mi][ni] = __builtin_amdgcn_mfma_f32_16x16x32_bf16(
                        a[mi], b[ni], acc[mi][ni], 0, 0, 0);
        }
    }

    // epilogue: LDS transpose -> coalesced NCHW stores (+bias). es aliases xs.
    float (*es)[16][68] = (float (*)[16][68])smem;
    for (int ni = 0; ni < 4; ++ni) {
        __syncthreads();
        for (int mi = 0; mi < 4; ++mi) {
            *(float4*)&es[wv][lr][mi * 16 + lq * 4] = *(const float4*)&acc[mi][ni];
        }
        __syncthreads();
        int row = lane >> 2;
        int cp  = lane & 3;
        int co = bn * 128 + nw * 64 + ni * 16 + row;
        float bco = bias[co];
        size_t obase = (((size_t)n * CO + co) * HH + h) * WW + mw * 64 + cp * 16;
#pragma unroll
        for (int q = 0; q < 4; ++q) {
            float4 tv = *(const float4*)&es[wv][row][cp * 16 + q * 4];
            tv.x += bco; tv.y += bco; tv.z += bco; tv.w += bco;
            *(float4*)(out + obase + q * 4) = tv;
        }
    }
}

// ---------------------------------------------------------------------------
// Fallback: direct fp32 conv (only if workspace too small)
// ---------------------------------------------------------------------------
__global__ void conv_direct(const float* __restrict__ x, const float* __restrict__ wsrc,
                            const float* __restrict__ bias, float* __restrict__ out) {
    int b = blockIdx.x;           // ((n*256+o)*128 + h)
    int w = threadIdx.x;
    int h = b & 127;
    int rest = b >> 7;
    int o = rest & 255, n = rest >> 8;
    const float s[3] = {0.7f, 1.0f, 0.7f};
    float acc = bias[o];
    for (int ci = 0; ci < 128; ++ci) {
        const float* xp = x + ((size_t)n * CI + ci) * HH * WW;
        const float* wp = wsrc + ((size_t)o * CI + ci) * 9;
        for (int i = 0; i < 3; ++i) {
            int r = h + i - 1;
            if ((unsigned)r >= 128u) continue;
            for (int j = 0; j < 3; ++j) {
                int c = w + j - 1;
                if ((unsigned)c >= 128u) continue;
                acc += xp[r * 128 + c] * wp[i * 3 + j] * s[i] * s[j];
            }
        }
    }
    out[(size_t)b * 128 + w] = acc;
}

extern "C" void kernel_launch(void* const* d_in, const int* in_sizes, int n_in,
                              void* d_out, int out_size, void* d_ws, size_t ws_size,
                              hipStream_t stream) {
    const float* x    = (const float*)d_in[0];
    const float* wsrc = (const float*)d_in[1];
    const float* bias = (const float*)d_in[2];
    float* out = (float*)d_out;

    const size_t wt_bytes = (size_t)9 * CO * CI * 2;              // 589,824
    const size_t xt_bytes = (size_t)NIMG * HP * WP * CI * 2;      // 69,222,400
    if (ws_size < wt_bytes + xt_bytes) {
        conv_direct<<<NIMG * CO * HH, 128, 0, stream>>>(x, wsrc, bias, out);
        return;
    }
    unsigned short* wt = (unsigned short*)d_ws;
    unsigned short* xt = (unsigned short*)((char*)d_ws + wt_bytes);

    xform_w<<<(9 * CO * CI) / 256, 256, 0, stream>>>(wsrc, wt);
    xform_x<<<NIMG * HP, 256, 0, stream>>>(x, xt);
    conv_mfma<<<NIMG * HH * 2, 256, 0, stream>>>(xt, wt, bias, out);
}

// Round 2
// 509.307 us; speedup vs baseline: 1.3296x; 1.3296x over previous
//
#include <hip/hip_runtime.h>

#define NIMG 16
#define CI   128
#define CO   256
#define HH   128
#define WW   128
#define HP   130
#define WP   130

typedef short bf16x8 __attribute__((ext_vector_type(8)));
typedef float f32x4  __attribute__((ext_vector_type(4)));

typedef __attribute__((address_space(3))) unsigned int as3_u32;
typedef __attribute__((address_space(1))) const unsigned int as1_u32;

__device__ __forceinline__ unsigned short f2bf(float f) {
    unsigned u = __builtin_bit_cast(unsigned, f);
    unsigned r = u + 0x7fffu + ((u >> 16) & 1u);   // RNE
    return (unsigned short)(r >> 16);
}

__device__ __forceinline__ void gload16(const unsigned short* g, void* lds) {
    // 16B per lane, HW writes lds_base + lane*16 (linear); source addr is per-lane.
    __builtin_amdgcn_global_load_lds((as1_u32*)g, (as3_u32*)lds, 16, 0, 0);
}

// ---------------------------------------------------------------------------
// Prep 1: weights OIHW fp32 -> wt[tap][co][ci] bf16, scaled by kx[i]*kx[j]
// ---------------------------------------------------------------------------
__global__ void xform_w(const float* __restrict__ wsrc, unsigned short* __restrict__ wt) {
    int idx = blockIdx.x * 256 + threadIdx.x;       // (tap*256 + o)*128 + ci
    int ci   = idx & 127;
    int rest = idx >> 7;
    int o    = rest & 255;
    int tap  = rest >> 8;
    int i = tap / 3, j = tap - 3 * i;
    const float s0 = 0.7f;
    float si = (i == 1) ? 1.0f : s0;
    float sj = (j == 1) ? 1.0f : s0;
    float v = wsrc[((o * 128 + ci) * 3 + i) * 3 + j] * si * sj;
    wt[idx] = f2bf(v);
}

// ---------------------------------------------------------------------------
// Prep 2: x NCHW fp32 -> PADDED xt [n][hp][wp][ci] bf16, borders zeroed.
// Phase 1 vectorized: float4 global loads, conflict-free swizzled LDS writes
// (XOR on c bits [2:1] keyed by (w>>3)&3). Phase 2: b128 reads + in-register
// word un-swizzle, 16B coalesced stores.
// ---------------------------------------------------------------------------
__global__ __launch_bounds__(256) void xform_x(const float* __restrict__ x,
                                               unsigned short* __restrict__ xt) {
    int bid = blockIdx.x;                  // n*130 + hp
    int n = bid / 130, hp = bid - n * 130;
    int t = threadIdx.x;
    size_t rowbase = (size_t)bid * WP * CI;          // elems at (n,hp,0,0)

    if (hp == 0 || hp == 129) {                      // zero border row
        int4 z = make_int4(0, 0, 0, 0);
        for (int c = t; c < (WP * CI * 2) / 16; c += 256)
            *(int4*)((char*)(xt + rowbase) + (size_t)c * 16) = z;
        return;
    }
    int h = hp - 1;

    __shared__ __align__(16) unsigned short ls[128][136];

#pragma unroll
    for (int k = 0; k < 16; ++k) {
        int idx = k * 256 + t;             // 0..4095
        int c  = idx >> 5;                 // 0..127
        int w4 = idx & 31;                 // float4 chunk along w
        float4 v = *(const float4*)&x[(((size_t)n * CI + c) * HH + h) * WW + w4 * 4];
        int px = ((w4 >> 1) & 3) << 1;     // XOR on c bits [2:1], same for j=0..3
        ls[w4 * 4 + 0][c ^ px] = f2bf(v.x);
        ls[w4 * 4 + 1][c ^ px] = f2bf(v.y);
        ls[w4 * 4 + 2][c ^ px] = f2bf(v.z);
        ls[w4 * 4 + 3][c ^ px] = f2bf(v.w);
    }
    // w-border zero chunks (independent of LDS)
    if (t < 32) {
        int side = t >> 4, part = t & 15;
        size_t o = rowbase + (side ? (size_t)129 * CI : 0) + part * 8;
        *(int4*)(xt + o) = make_int4(0, 0, 0, 0);
    }
    __syncthreads();

    size_t obase = rowbase + CI;           // wp = 1
    for (int it = 0; it < 8; ++it) {
        int chunk = it * 256 + t;          // 0..2047
        int ww = chunk >> 4, cp = chunk & 15;
        int4 v = *(const int4*)&ls[ww][cp * 8];
        int s = (ww >> 3) & 3;
        int4 o = v;
        if (s & 1) o = make_int4(o.y, o.x, o.w, o.z);
        if (s & 2) o = make_int4(o.z, o.w, o.x, o.y);
        *(int4*)((char*)(xt + obase) + (size_t)chunk * 16) = o;
    }
}

// ---------------------------------------------------------------------------
// Main: implicit-GEMM conv, 128 px x 128 co per block, 4 waves, acc 4x4.
// K = 1152 split into 36 steps (kc 0..3 x tap 0..8). Per step: weights
// [128co][32ci] double-buffered in LDS (8 gload16/block), 2-phase pipeline
// (raw barrier + vmcnt(0), stage t+1 issued after barrier t). xs halo
// (3x130 px x 32ci) single-buffered, prefetched at kc boundaries.
// XOR slot swizzles on both xs and ws kill ds_read_b128 bank conflicts.
// ---------------------------------------------------------------------------
__global__ __launch_bounds__(256, 3) void conv_mfma(const unsigned short* __restrict__ xt,
                                                    const unsigned short* __restrict__ wt,
                                                    const float* __restrict__ bias,
                                                    float* __restrict__ out) {
    // bijective XCD swizzle: nwg=4096, 512 contiguous work items per XCD
    int bid0 = blockIdx.x;
    int wk  = (bid0 & 7) * 512 + (bid0 >> 3);
    int bn  = wk & 1;             // co half
    int bm  = wk >> 1;            // (n,h)
    int n = bm >> 7, h = bm & 127;
    int tid  = threadIdx.x;
    int lane = tid & 63, wv = tid >> 6;
    int mw = wv & 1, nw = wv >> 1;
    int lr = lane & 15;
    int lq = lane >> 4;

    // LDS: ws[2] @0 (2*8192), xs @16384 (1792*16 = 28672 incl staging slack)
    __shared__ __align__(1024) char smem[45056];
    char* xsb = smem + 16384;

    f32x4 acc[4][4];
    const f32x4 zero = {0.0f, 0.0f, 0.0f, 0.0f};
    for (int mi = 0; mi < 4; ++mi)
        for (int ni = 0; ni < 4; ++ni) acc[mi][ni] = zero;

    int pm[4];                    // A pixel index per mi
    for (int mi = 0; mi < 4; ++mi) pm[mi] = mw * 64 + mi * 16 + lr;
    // B read offset (byte, within ws buffer, +ni*1024 per frag)
    int boff = (nw * 64 + lr) * 64 + ((lq ^ ((lr >> 1) & 3)) << 4);

    // ws staging source invariants: chunk c = (co<<2)|slot, q = slot^((co>>1)&3)
    int wsrc_off[2];
#pragma unroll
    for (int i = 0; i < 2; ++i) {
        int c = wv * 128 + i * 64 + lane;          // 0..511
        int co = c >> 2, slot = c & 3;
        int q = slot ^ ((co >> 1) & 3);
        wsrc_off[i] = (bn * 128 + co) * CI + q * 8;
    }

    // xs staging source invariants: chunk c = (p<<2)|slot, q = slot^((p>>1)&3)
    int goffs[7];
    int nbase = n * (HP * WP * CI);
#pragma unroll
    for (int i = 0; i < 7; ++i) {
        int c = wv * 448 + i * 64 + lane;
        int pp = (c < 1560) ? (c >> 2) : 0;       // clamp tail chunks in-bounds
        int slot = c & 3;
        int q = slot ^ ((pp >> 1) & 3);
        int dh = (pp * 505) >> 16;                // pp / 130 for pp < 390
        int wp = pp - dh * 130;
        goffs[i] = nbase + ((h + dh) * WP + wp) * CI + q * 8;
    }

    auto stage_ws = [&](int par, int kc_, int tap_) {
        const unsigned short* src = wt + (size_t)tap_ * CO * CI + kc_ * 32;
#pragma unroll
        for (int i = 0; i < 2; ++i)
            gload16(src + wsrc_off[i], smem + par * 8192 + wv * 2048 + i * 1024);
    };
    auto stage_xs = [&](int kc_) {
#pragma unroll
        for (int i = 0; i < 7; ++i)
            gload16(xt + goffs[i] + kc_ * 32, xsb + wv * 7168 + i * 1024);
    };

    // prologue
    stage_xs(0);
    stage_ws(0, 0, 0);

#pragma unroll 1
    for (int kc = 0; kc < 4; ++kc) {
#pragma unroll
        for (int tap = 0; tap < 9; ++tap) {
            asm volatile("s_waitcnt vmcnt(0)" ::: "memory");
            __builtin_amdgcn_s_barrier();
            __builtin_amdgcn_sched_barrier(0);
            if (tap < 8) stage_ws((kc + tap + 1) & 1, kc, tap + 1);

            const char* wsb = smem + ((kc + tap) & 1) * 8192;
            int di = tap / 3, dj = tap - 3 * di;
            int pd = di * 130 + dj;
            bf16x8 a[4], b[4];
#pragma unroll
            for (int mi = 0; mi < 4; ++mi) {
                int p = pd + pm[mi];
                int sw = (p >> 1) & 3;
                a[mi] = *(const bf16x8*)(xsb + p * 64 + ((lq ^ sw) << 4));
            }
#pragma unroll
            for (int ni = 0; ni < 4; ++ni)
                b[ni] = *(const bf16x8*)(wsb + ni * 1024 + boff);
#pragma unroll
            for (int mi = 0; mi < 4; ++mi)
#pragma unroll
                for (int ni = 0; ni < 4; ++ni)
                    acc[mi][ni] = __builtin_amdgcn_mfma_f32_16x16x32_bf16(
                        a[mi], b[ni], acc[mi][ni], 0, 0, 0);
        }
        if (kc < 3) {
            // all waves finished this kc's xs reads (consumed by MFMAs pre-barrier)
            __builtin_amdgcn_s_barrier();
            __builtin_amdgcn_sched_barrier(0);
            stage_xs(kc + 1);
            stage_ws((kc + 1) & 1, kc + 1, 0);
        }
    }

    // epilogue: LDS transpose -> coalesced NCHW stores (+bias). es aliases smem.
    float (*es)[16][68] = (float (*)[16][68])smem;
    for (int ni = 0; ni < 4; ++ni) {
        __syncthreads();
        for (int mi = 0; mi < 4; ++mi) {
            *(float4*)&es[wv][lr][mi * 16 + lq * 4] = *(const float4*)&acc[mi][ni];
        }
        __syncthreads();
        int row = lane >> 2;
        int cp  = lane & 3;
        int co = bn * 128 + nw * 64 + ni * 16 + row;
        float bco = bias[co];
        size_t obase = (((size_t)n * CO + co) * HH + h) * WW + mw * 64 + cp * 16;
#pragma unroll
        for (int q = 0; q < 4; ++q) {
            float4 tv = *(const float4*)&es[wv][row][cp * 16 + q * 4];
            tv.x += bco; tv.y += bco; tv.z += bco; tv.w += bco;
            *(float4*)(out + obase + q * 4) = tv;
        }
    }
}

// ---------------------------------------------------------------------------
// Fallback: direct fp32 conv (only if workspace too small)
// ---------------------------------------------------------------------------
__global__ void conv_direct(const float* __restrict__ x, const float* __restrict__ wsrc,
                            const float* __restrict__ bias, float* __restrict__ out) {
    int b = blockIdx.x;           // ((n*256+o)*128 + h)
    int w = threadIdx.x;
    int h = b & 127;
    int rest = b >> 7;
    int o = rest & 255, n = rest >> 8;
    const float s[3] = {0.7f, 1.0f, 0.7f};
    float acc = bias[o];
    for (int ci = 0; ci < 128; ++ci) {
        const float* xp = x + ((size_t)n * CI + ci) * HH * WW;
        const float* wp = wsrc + ((size_t)o * CI + ci) * 9;
        for (int i = 0; i < 3; ++i) {
            int r = h + i - 1;
            if ((unsigned)r >= 128u) continue;
            for (int j = 0; j < 3; ++j) {
                int c = w + j - 1;
                if ((unsigned)c >= 128u) continue;
                acc += xp[r * 128 + c] * wp[i * 3 + j] * s[i] * s[j];
            }
        }
    }
    out[(size_t)b * 128 + w] = acc;
}

extern "C" void kernel_launch(void* const* d_in, const int* in_sizes, int n_in,
                              void* d_out, int out_size, void* d_ws, size_t ws_size,
                              hipStream_t stream) {
    const float* x    = (const float*)d_in[0];
    const float* wsrc = (const float*)d_in[1];
    const float* bias = (const float*)d_in[2];
    float* out = (float*)d_out;

    const size_t wt_bytes = (size_t)9 * CO * CI * 2;              // 589,824
    const size_t xt_bytes = (size_t)NIMG * HP * WP * CI * 2;      // 69,222,400
    if (ws_size < wt_bytes + xt_bytes) {
        conv_direct<<<NIMG * CO * HH, 128, 0, stream>>>(x, wsrc, bias, out);
        return;
    }
    unsigned short* wt = (unsigned short*)d_ws;
    unsigned short* xt = (unsigned short*)((char*)d_ws + wt_bytes);

    xform_w<<<(9 * CO * CI) / 256, 256, 0, stream>>>(wsrc, wt);
    xform_x<<<NIMG * HP, 256, 0, stream>>>(x, xt);
    conv_mfma<<<NIMG * HH * 2, 256, 0, stream>>>(xt, wt, bias, out);
}